// Round 1
// baseline (1563.937 us; speedup 1.0000x reference)
//
#include <hip/hip_runtime.h>
#include <cstdint>

// Problem: input [32,64,64,256] fp32 = 131072 rows x 256; embed [256,2048] fp32.
// d_out (fp32): quantize[33554432] | diff[1] | embed_ind_as_float[131072]
//
// Strategy: split-bf16 MFMA distance GEMM (xh+xl)(eh+el) with 3 MFMA terms,
// per-row top-2 candidate tracking, then exact fp32 refine of the 2 candidates
// fused with the gather/straight-through/diff epilogue.
//
// R1: non-temporal loads for the streaming input (pass1 staging, refine) and
//     NT store for q_out -> keep the 2 MB packed codebook L2-resident
//     (FETCH_SIZE showed ~2.7 GB = codebook thrashed out of L2 by the input
//     stream). Plus s_setprio around MFMA clusters (waves are phase-diverse:
//     no barriers in the chunk loop).

#define NROWS   131072
#define DIM     256
#define NE      2048
#define BM      64                    // rows per pass1 block
#define NBLK_P1 (NROWS / BM)          // 2048
#define GROWS   4
#define NBLK_RG (NROWS / GROWS)       // 32768

typedef __attribute__((ext_vector_type(8))) short bf16x8;
typedef __attribute__((ext_vector_type(4))) float f32x4;

__device__ __forceinline__ ushort bf16_rne(float v) {
  uint u = __float_as_uint(v);
  return (ushort)((u + 0x7FFFu + ((u >> 16) & 1u)) >> 16);
}
__device__ __forceinline__ void split_hi_lo(float v, ushort& h, ushort& l) {
  h = bf16_rne(v);
  const float hf = __uint_as_float(((uint)h) << 16);
  l = bf16_rne(v - hf);
}

// ---------------------------------------------------------------------------
// enorm[j] = sum_d embed[d][j]^2   (fp32, matches round-1 validated math)
// ---------------------------------------------------------------------------
__global__ __launch_bounds__(256) void enorm_kernel(
    const float* __restrict__ embed, float* __restrict__ enorm) {
  const int j = blockIdx.x * 256 + threadIdx.x;
  float s = 0.f;
#pragma unroll 8
  for (int d = 0; d < DIM; ++d) {
    const float v = embed[(size_t)d * NE + j];
    s = fmaf(v, v, s);
  }
  enorm[j] = s;
}

// ---------------------------------------------------------------------------
// embT[j][d] = embed[d][j]
// ---------------------------------------------------------------------------
__global__ __launch_bounds__(256) void transpose_kernel(
    const float* __restrict__ embed, float* __restrict__ embT) {
  __shared__ float tile[32][33];
  const int tx = threadIdx.x;  // 0..31
  const int ty = threadIdx.y;  // 0..7
  const int j0 = blockIdx.x * 32;
  const int d0 = blockIdx.y * 32;
#pragma unroll
  for (int i = 0; i < 4; ++i) {
    const int dd = ty + i * 8;
    tile[dd][tx] = embed[(size_t)(d0 + dd) * NE + j0 + tx];
  }
  __syncthreads();
#pragma unroll
  for (int i = 0; i < 4; ++i) {
    const int jj = ty + i * 8;
    embT[(size_t)(j0 + jj) * DIM + d0 + tx] = tile[tx][jj];
  }
}

// ---------------------------------------------------------------------------
// Pack embed into bf16 hi/lo in MFMA-B-fragment order:
// ebh4[(ct*8+ks)*64 + lane] = 8 bf16 of code ct*16+(lane&15),
//                             k = ks*32 + (lane>>4)*8 .. +7
// so the pass1 wave's B-frag load is one fully-coalesced 1 KB b128 read.
// ---------------------------------------------------------------------------
__global__ __launch_bounds__(256) void pack_embed_kernel(
    const float* __restrict__ embT, uint4* __restrict__ ebh4,
    uint4* __restrict__ ebl4) {
  const int g    = blockIdx.x * 256 + threadIdx.x;  // 0..65535
  const int ct   = g >> 9;
  const int r    = g & 511;
  const int ks   = r >> 6;
  const int lane = r & 63;
  const int code = ct * 16 + (lane & 15);
  const int k0   = ks * 32 + (lane >> 4) * 8;
  const float* src = embT + (size_t)code * DIM + k0;
  const float4 a = *(const float4*)(src);
  const float4 b = *(const float4*)(src + 4);
  ushort h[8], l[8];
  split_hi_lo(a.x, h[0], l[0]); split_hi_lo(a.y, h[1], l[1]);
  split_hi_lo(a.z, h[2], l[2]); split_hi_lo(a.w, h[3], l[3]);
  split_hi_lo(b.x, h[4], l[4]); split_hi_lo(b.y, h[5], l[5]);
  split_hi_lo(b.z, h[6], l[6]); split_hi_lo(b.w, h[7], l[7]);
  uint4 hv, lv;
  hv.x = (uint)h[0] | ((uint)h[1] << 16); hv.y = (uint)h[2] | ((uint)h[3] << 16);
  hv.z = (uint)h[4] | ((uint)h[5] << 16); hv.w = (uint)h[6] | ((uint)h[7] << 16);
  lv.x = (uint)l[0] | ((uint)l[1] << 16); lv.y = (uint)l[2] | ((uint)l[3] << 16);
  lv.z = (uint)l[4] | ((uint)l[5] << 16); lv.w = (uint)l[6] | ((uint)l[7] << 16);
  ebh4[g] = hv;
  ebl4[g] = lv;
}

// ---------------------------------------------------------------------------
// Pass 1: split-bf16 MFMA distance GEMM + per-row top-2.
// Block = 256 thr (4 waves), 64 rows. A (hi/lo) staged in LDS in A-frag order.
// Wave w owns codes [w*512, w*512+512), in 8 chunks of 64 (4 n-tiles).
// Per k-step: 8 ds_read_b128 (A) + 8 global b128 (B, L2-resident) + 48 MFMA.
// dist = enorm[j] - 2*score (row-constant ||x||^2 dropped, order-preserving).
// Top-2 per (lane,row) -> LDS merge -> exact block top-2 -> packed u16 pair.
// Input staging uses NT loads so the streaming input does not evict the
// codebook from L2.
// ---------------------------------------------------------------------------
__global__ __launch_bounds__(256, 2) void pass1_kernel(
    const float* __restrict__ inp, const uint4* __restrict__ ebh4,
    const uint4* __restrict__ ebl4, const float* __restrict__ enorm,
    uint* __restrict__ cand) {
  __shared__ __align__(16) uint smem[16384];  // 64 KB
  ushort* AhL = (ushort*)smem;                // 32 KB
  ushort* AlL = AhL + 16384;                  // 32 KB
  const int t  = threadIdx.x;
  const int r0 = blockIdx.x * BM;

  // Stage A: fp32 -> bf16 hi/lo, A-frag layout:
  // index = ((rt*8+ks)*64 + kg*16 + m)*8 + j  for element (row=rt*16+m, k=ks*32+kg*8+j)
  {
    const int row = t >> 2, kq = t & 3;
    const int art = row >> 4, m = row & 15;
    const f32x4* src = (const f32x4*)(inp + (size_t)(r0 + row) * DIM);
#pragma unroll
    for (int c = 0; c < 16; ++c) {
      const int k4 = c * 4 + kq;
      const f32x4 v = __builtin_nontemporal_load(src + k4);  // NT: stream input
      const int k = k4 * 4;
      const int aks = k >> 5, akg = (k >> 3) & 3, j = k & 7;
      const int idx = ((art * 8 + aks) * 64 + akg * 16 + m) * 8 + j;
      ushort h0, h1, h2, h3, l0, l1, l2, l3;
      split_hi_lo(v[0], h0, l0); split_hi_lo(v[1], h1, l1);
      split_hi_lo(v[2], h2, l2); split_hi_lo(v[3], h3, l3);
      ushort4 hv; hv.x = h0; hv.y = h1; hv.z = h2; hv.w = h3;
      ushort4 lv; lv.x = l0; lv.y = l1; lv.z = l2; lv.w = l3;
      *(ushort4*)(AhL + idx) = hv;
      *(ushort4*)(AlL + idx) = lv;
    }
  }
  __syncthreads();

  const int wv = t >> 6, lane = t & 63, col = lane & 15, kg = lane >> 4;
  float td1[16], td2[16];
  uint  ti[16];  // low16 = best idx, high16 = second idx
#pragma unroll
  for (int i = 0; i < 16; ++i) { td1[i] = 3.4e38f; td2[i] = 3.4e38f; ti[i] = 0u; }

  for (int ch = 0; ch < 8; ++ch) {
    const int cb  = wv * 512 + ch * 64;
    const int ctb = cb >> 4;
    f32x4 acc[4][4];
#pragma unroll
    for (int rt = 0; rt < 4; ++rt)
#pragma unroll
      for (int nt = 0; nt < 4; ++nt) acc[rt][nt] = (f32x4){0.f, 0.f, 0.f, 0.f};

#pragma unroll
    for (int ks = 0; ks < 8; ++ks) {
      bf16x8 ah[4], al[4], bh[4], bl[4];
#pragma unroll
      for (int nt = 0; nt < 4; ++nt) {
        const int bi = (ctb + nt) * 512 + ks * 64 + lane;
        bh[nt] = *(const bf16x8*)(ebh4 + bi);
        bl[nt] = *(const bf16x8*)(ebl4 + bi);
      }
#pragma unroll
      for (int rt = 0; rt < 4; ++rt) {
        const int ai = ((rt * 8 + ks) * 64 + lane) * 8;
        ah[rt] = *(const bf16x8*)(AhL + ai);
        al[rt] = *(const bf16x8*)(AlL + ai);
      }
      __builtin_amdgcn_s_setprio(1);
#pragma unroll
      for (int rt = 0; rt < 4; ++rt)
#pragma unroll
        for (int nt = 0; nt < 4; ++nt) {
          acc[rt][nt] = __builtin_amdgcn_mfma_f32_16x16x32_bf16(
              ah[rt], bh[nt], acc[rt][nt], 0, 0, 0);
          acc[rt][nt] = __builtin_amdgcn_mfma_f32_16x16x32_bf16(
              ah[rt], bl[nt], acc[rt][nt], 0, 0, 0);
          acc[rt][nt] = __builtin_amdgcn_mfma_f32_16x16x32_bf16(
              al[rt], bh[nt], acc[rt][nt], 0, 0, 0);
        }
      __builtin_amdgcn_s_setprio(0);
    }

    // epilogue: dist + top-2 update (codes ascend -> first-occurrence ties)
#pragma unroll
    for (int nt = 0; nt < 4; ++nt) {
      const uint code = (uint)(cb + nt * 16 + col);
      const float en  = enorm[code];
#pragma unroll
      for (int rt = 0; rt < 4; ++rt)
#pragma unroll
        for (int reg = 0; reg < 4; ++reg) {
          const float dd = fmaf(-2.f, acc[rt][nt][reg], en);
          const int ri = rt * 4 + reg;
          if (dd < td1[ri]) {
            td2[ri] = td1[ri];
            ti[ri]  = (ti[ri] << 16) | code;
            td1[ri] = dd;
          } else if (dd < td2[ri]) {
            td2[ri] = dd;
            ti[ri]  = (ti[ri] & 0xFFFFu) | (code << 16);
          }
        }
    }
  }

  // Cross-wave merge: per row, 64 slots x 2 candidates in LDS (reuses A area).
  __syncthreads();
  float* rdF = (float*)smem;
  uint*  rdI = smem;
#pragma unroll
  for (int rt = 0; rt < 4; ++rt)
#pragma unroll
    for (int reg = 0; reg < 4; ++reg) {
      const int ri   = rt * 4 + reg;
      const int row  = rt * 16 + kg * 4 + reg;
      const int slot = wv * 16 + col;
      const int base = (row * 64 + slot) * 4;
      rdF[base + 0] = td1[ri];
      rdI[base + 1] = ti[ri] & 0xFFFFu;
      rdF[base + 2] = td2[ri];
      rdI[base + 3] = ti[ri] >> 16;
    }
  __syncthreads();
  if (t < BM) {
    float D1 = 3.4e38f, D2 = 3.4e38f;
    uint  I1 = 0xFFFFu, I2 = 0xFFFFu;
    for (int s = 0; s < 64; ++s) {
      const int base = (t * 64 + s) * 4;
#pragma unroll
      for (int c = 0; c < 2; ++c) {
        const float d = rdF[base + c * 2];
        const uint  i = rdI[base + c * 2 + 1];
        if (d < D1 || (d == D1 && i < I1)) {
          D2 = D1; I2 = I1; D1 = d; I1 = i;
        } else if (d < D2 || (d == D2 && i < I2)) {
          D2 = d; I2 = i;
        }
      }
    }
    cand[r0 + t] = I1 | (I2 << 16);
  }
}

// ---------------------------------------------------------------------------
// Refine + gather + diff: exact fp32 distances for the 2 candidates, pick
// winner (first-occurrence tie-break), codebook lookup, straight-through
// output q = x + (e - x), per-block diff partial. Candidates are read from
// the idx_out region (bit-packed u32) and overwritten with the float index.
// NT on the input stream + q_out stream; embT/enorm stay cached.
// ---------------------------------------------------------------------------
__global__ __launch_bounds__(256) void refine_gather_kernel(
    const float* __restrict__ inp, const float* __restrict__ embT,
    const float* __restrict__ enorm, float* __restrict__ q_out,
    float* __restrict__ idx_out, float* __restrict__ partials) {
  __shared__ float wsum[4];
  const int t    = threadIdx.x;
  const int row  = blockIdx.x * GROWS + (t >> 6);
  const int lane = t & 63;
  const int d4   = lane * 4;

  const uint u = ((const uint*)idx_out)[row];
  const int i1 = (int)(u & 0xFFFFu);
  const int i2 = (int)(u >> 16);

  const f32x4 x  = __builtin_nontemporal_load(
      (const f32x4*)(inp + (size_t)row * DIM + d4));
  const f32x4 e1 = *(const f32x4*)(embT + (size_t)i1 * DIM + d4);
  const f32x4 e2 = *(const f32x4*)(embT + (size_t)i2 * DIM + d4);

  float s1 = x[0] * e1[0] + x[1] * e1[1] + x[2] * e1[2] + x[3] * e1[3];
  float s2 = x[0] * e2[0] + x[1] * e2[1] + x[2] * e2[2] + x[3] * e2[3];
#pragma unroll
  for (int o = 32; o > 0; o >>= 1) {
    s1 += __shfl_xor(s1, o, 64);
    s2 += __shfl_xor(s2, o, 64);
  }
  const float dd1 = fmaf(-2.f, s1, enorm[i1]);
  const float dd2 = fmaf(-2.f, s2, enorm[i2]);
  const bool take2 = (dd2 < dd1) || (dd2 == dd1 && i2 < i1);
  const f32x4 e = take2 ? e2 : e1;
  const int  win = take2 ? i2 : i1;

  f32x4 dq, q;
  dq[0] = e[0] - x[0]; dq[1] = e[1] - x[1];
  dq[2] = e[2] - x[2]; dq[3] = e[3] - x[3];
  q[0] = x[0] + dq[0]; q[1] = x[1] + dq[1];
  q[2] = x[2] + dq[2]; q[3] = x[3] + dq[3];
  __builtin_nontemporal_store(q, (f32x4*)(q_out + (size_t)row * DIM + d4));
  if (lane == 0) idx_out[row] = (float)win;

  float s = dq[0] * dq[0] + dq[1] * dq[1] + dq[2] * dq[2] + dq[3] * dq[3];
#pragma unroll
  for (int o = 32; o > 0; o >>= 1) s += __shfl_down(s, o, 64);
  if (lane == 0) wsum[t >> 6] = s;
  __syncthreads();
  if (t == 0) partials[blockIdx.x] = wsum[0] + wsum[1] + wsum[2] + wsum[3];
}

// ---------------------------------------------------------------------------
__global__ __launch_bounds__(256) void final_diff_kernel(
    const float* __restrict__ partials, float* __restrict__ diff_out) {
  __shared__ float wsum[4];
  const int t = threadIdx.x;
  float s = 0.f;
  for (int k = 0; k < NBLK_RG / 256; ++k) s += partials[t + k * 256];
#pragma unroll
  for (int o = 32; o > 0; o >>= 1) s += __shfl_down(s, o, 64);
  if ((t & 63) == 0) wsum[t >> 6] = s;
  __syncthreads();
  if (t == 0) {
    const float total = wsum[0] + wsum[1] + wsum[2] + wsum[3];
    diff_out[0] = total * (1.0f / (float)((size_t)NROWS * DIM));
  }
}

// ---------------------------------------------------------------------------
extern "C" void kernel_launch(void* const* d_in, const int* in_sizes, int n_in,
                              void* d_out, int out_size, void* d_ws,
                              size_t ws_size, hipStream_t stream) {
  (void)in_sizes; (void)n_in; (void)out_size; (void)ws_size;
  const float* inp   = (const float*)d_in[0];
  const float* embed = (const float*)d_in[1];

  float* out      = (float*)d_out;
  float* q_out    = out;                        // 33554432 floats
  float* diff_out = out + (size_t)NROWS * DIM;  // 1 float
  float* idx_out  = diff_out + 1;               // 131072 floats (cand scratch)

  float* ws       = (float*)d_ws;
  float* embT     = ws;                          // 524288 floats (2 MB)
  float* enorm    = ws + (size_t)NE * DIM;       // 2048 floats
  float* partials = enorm + NE;                  // 32768 floats
  float* ebh      = partials + NBLK_RG;          // 262144 floats (1 MB as bf16)
  float* ebl      = ebh + (size_t)NE * DIM / 2;  // 262144 floats (1 MB as bf16)
  uint4* ebh4     = (uint4*)ebh;
  uint4* ebl4     = (uint4*)ebl;

  enorm_kernel<<<NE / 256, 256, 0, stream>>>(embed, enorm);
  transpose_kernel<<<dim3(NE / 32, DIM / 32), dim3(32, 8), 0, stream>>>(embed, embT);
  pack_embed_kernel<<<(NE / 16) * 8 * 64 / 256, 256, 0, stream>>>(embT, ebh4, ebl4);
  pass1_kernel<<<NBLK_P1, 256, 0, stream>>>(inp, ebh4, ebl4, enorm,
                                            (uint*)idx_out);
  refine_gather_kernel<<<NBLK_RG, 256, 0, stream>>>(inp, embT, enorm, q_out,
                                                    idx_out, partials);
  final_diff_kernel<<<1, 256, 0, stream>>>(partials, diff_out);
}